// Round 9
// baseline (457.405 us; speedup 1.0000x reference)
//
#include <hip/hip_runtime.h>
#include <hip/hip_bf16.h>
#include <math.h>

typedef __bf16 bf16;
typedef bf16 bf16x4 __attribute__((ext_vector_type(4)));
typedef bf16 bf16x8 __attribute__((ext_vector_type(8)));
typedef float f32x4 __attribute__((ext_vector_type(4)));

#define B_ 4
#define S_ 2048
#define HID_ 1024
#define NH_ 16
#define HD_ 64
#define LTS 72   // padded LDS tile stride (qkv epilogue)

// async global->LDS, 16B per lane. LDS dest must be wave-uniform base + lane*16.
__device__ __forceinline__ void async16(const bf16* g, bf16* l) {
  __builtin_amdgcn_global_load_lds(
      (const __attribute__((address_space(1))) void*)g,
      (__attribute__((address_space(3))) void*)l, 16, 0, 0);
}

#define MM16(A, B, C) C = __builtin_amdgcn_mfma_f32_16x16x32_bf16(A, B, C, 0, 0, 0)

// ---------------- fp32 -> bf16 convert
__global__ void cvt_kernel(const float* __restrict__ src, bf16* __restrict__ dst, int n4) {
  int i = blockIdx.x * 256 + threadIdx.x;
  if (i < n4) {
    float4 v = ((const float4*)src)[i];
    bf16x4 o;
    o[0] = (bf16)v.x; o[1] = (bf16)v.y; o[2] = (bf16)v.z; o[3] = (bf16)v.w;
    ((bf16x4*)dst)[i] = o;
  }
}

#define DECL_ACC \
  f32x4 a00 = {}, a01 = {}, a02 = {}, a03 = {}; \
  f32x4 a10 = {}, a11 = {}, a12 = {}, a13 = {}; \
  f32x4 a20 = {}, a21 = {}, a22 = {}, a23 = {}; \
  f32x4 a30 = {}, a31 = {}, a32 = {}, a33 = {};

#define KLOOP_FRAGS_MFMA \
    bf16x8 af0 = *(const bf16x8*)(lA + (wm + 0 * 16 + l16) * 32 + quad * 8); \
    bf16x8 af1 = *(const bf16x8*)(lA + (wm + 1 * 16 + l16) * 32 + quad * 8); \
    bf16x8 af2 = *(const bf16x8*)(lA + (wm + 2 * 16 + l16) * 32 + quad * 8); \
    bf16x8 af3 = *(const bf16x8*)(lA + (wm + 3 * 16 + l16) * 32 + quad * 8); \
    bf16x8 bg0 = *(const bf16x8*)(lB + (wn + 0 * 16 + l16) * 32 + quad * 8); \
    bf16x8 bg1 = *(const bf16x8*)(lB + (wn + 1 * 16 + l16) * 32 + quad * 8); \
    bf16x8 bg2 = *(const bf16x8*)(lB + (wn + 2 * 16 + l16) * 32 + quad * 8); \
    bf16x8 bg3 = *(const bf16x8*)(lB + (wn + 3 * 16 + l16) * 32 + quad * 8); \
    MM16(af0, bg0, a00); MM16(af0, bg1, a01); MM16(af0, bg2, a02); MM16(af0, bg3, a03); \
    MM16(af1, bg0, a10); MM16(af1, bg1, a11); MM16(af1, bg2, a12); MM16(af1, bg3, a13); \
    MM16(af2, bg0, a20); MM16(af2, bg1, a21); MM16(af2, bg2, a22); MM16(af2, bg3, a23); \
    MM16(af3, bg0, a30); MM16(af3, bg1, a31); MM16(af3, bg2, a32); MM16(af3, bg3, a33);

#define ROPE_R(i, r, C0, C1, C2, C3) { \
  const int mloc = (i) * 16 + quad * 4 + (r); \
  const float p = (float)pos[mbase + mloc]; \
  const float aa0 = p * invf0, aa1 = p * invf1; \
  const float c0 = __cosf(aa0), sn0 = __sinf(aa0); \
  const float c1 = __cosf(aa1), sn1 = __sinf(aa1); \
  myT[mloc * LTS + l16]      = (bf16)((C0[r] * c0 - C2[r] * sn0) * scl); \
  myT[mloc * LTS + 32 + l16] = (bf16)((C2[r] * c0 + C0[r] * sn0) * scl); \
  myT[mloc * LTS + 16 + l16] = (bf16)((C1[r] * c1 - C3[r] * sn1) * scl); \
  myT[mloc * LTS + 48 + l16] = (bf16)((C3[r] * c1 + C1[r] * sn1) * scl); }
#define ROPE_I(i, C0, C1, C2, C3) \
  ROPE_R(i, 0, C0, C1, C2, C3) ROPE_R(i, 1, C0, C1, C2, C3) \
  ROPE_R(i, 2, C0, C1, C2, C3) ROPE_R(i, 3, C0, C1, C2, C3)

#define VW(i, j, C) { \
  bf16x4 o; o[0] = (bf16)C[0]; o[1] = (bf16)C[1]; o[2] = (bf16)C[2]; o[3] = (bf16)C[3]; \
  *(bf16x4*)(myT + ((j) * 16 + l16) * LTS + (i) * 16 + quad * 4) = o; }

// ---------------- QKV GEMM: Y = Xb @ Wb^T, fused RoPE.
__global__ void qkv_gemm(
    const bf16* __restrict__ X, const bf16* __restrict__ Wq,
    const bf16* __restrict__ Wk, const bf16* __restrict__ Wv,
    const int* __restrict__ pos,
    bf16* __restrict__ Q, bf16* __restrict__ Ko, bf16* __restrict__ Vt) {
  const int z = blockIdx.z;
  const bf16* W = (z == 0) ? Wq : (z == 1) ? Wk : Wv;
  const int m0 = blockIdx.y * 128;
  const int n0 = blockIdx.x * 128;
  __shared__ __align__(16) bf16 lA[128 * 32];
  __shared__ __align__(16) bf16 lB[128 * 32];
  __shared__ __align__(16) bf16 lT[4][64 * LTS];
  const int tid = threadIdx.x;
  const int lane = tid & 63, w = tid >> 6;
  const int wm = (w >> 1) * 64, wn = (w & 1) * 64;
  const int quad = lane >> 4, l16 = lane & 15;

  DECL_ACC

  const int qa = tid, qb = tid + 256;
  const int ra = qa >> 2, ca = (qa & 3) * 8;
  const int rb = qb >> 2, cb = (qb & 3) * 8;

  for (int k0 = 0; k0 < 1024; k0 += 32) {
    async16(X + (size_t)(m0 + ra) * 1024 + k0 + ca, lA + qa * 8);
    async16(X + (size_t)(m0 + rb) * 1024 + k0 + cb, lA + qb * 8);
    async16(W + (size_t)(n0 + ra) * 1024 + k0 + ca, lB + qa * 8);
    async16(W + (size_t)(n0 + rb) * 1024 + k0 + cb, lB + qb * 8);
    __syncthreads();
    KLOOP_FRAGS_MFMA
    __syncthreads();
  }

  const int h = (n0 + wn) >> 6;
  const int mbase = m0 + wm;
  const int b = mbase >> 11, s0 = mbase & 2047;
  bf16* myT = lT[w];

  if (z <= 1) {
    const float scl = (z == 0) ? 0.125f : 1.0f;
    const float invf0 = __expf(-0.28782313662425572f * (float)l16);   // ln(1e4)/32
    const float invf1 = __expf(-0.28782313662425572f * (float)(16 + l16));
    ROPE_I(0, a00, a01, a02, a03)
    ROPE_I(1, a10, a11, a12, a13)
    ROPE_I(2, a20, a21, a22, a23)
    ROPE_I(3, a30, a31, a32, a33)
    asm volatile("s_waitcnt lgkmcnt(0)" ::: "memory");
    bf16* dst = (z == 0) ? Q : Ko;
    const int rr = lane >> 3, cc = lane & 7;
#pragma unroll
    for (int it = 0; it < 8; it++) {
      int mloc = it * 8 + rr;
      bf16x8 v = *(const bf16x8*)(myT + mloc * LTS + cc * 8);
      *(bf16x8*)(dst + (((size_t)b * NH_ + h) * S_ + s0 + mloc) * HD_ + cc * 8) = v;
    }
  } else {
    VW(0, 0, a00) VW(0, 1, a01) VW(0, 2, a02) VW(0, 3, a03)
    VW(1, 0, a10) VW(1, 1, a11) VW(1, 2, a12) VW(1, 3, a13)
    VW(2, 0, a20) VW(2, 1, a21) VW(2, 2, a22) VW(2, 3, a23)
    VW(3, 0, a30) VW(3, 1, a31) VW(3, 2, a32) VW(3, 3, a33)
    asm volatile("s_waitcnt lgkmcnt(0)" ::: "memory");
    const int rr = lane >> 3, cc = lane & 7;
#pragma unroll
    for (int it = 0; it < 8; it++) {
      int d = it * 8 + rr;
      bf16x8 v = *(const bf16x8*)(myT + d * LTS + cc * 8);
      *(bf16x8*)(Vt + (((size_t)b * NH_ + h) * HD_ + d) * S_ + s0 + cc * 8) = v;
    }
  }
}

// softmax for one row-group; all in-lane for q-row l16, cross-quad via 2 shfls.
#define SOFTMAX_G(sg0, sg1, sg2, sg3, f0, f1, f2, f3, MR, LR, myP, og0, og1, og2, og3) { \
  float v00 = sg0[0] + f0.x, v01 = sg0[1] + f0.y, v02 = sg0[2] + f0.z, v03 = sg0[3] + f0.w; \
  float v10 = sg1[0] + f1.x, v11 = sg1[1] + f1.y, v12 = sg1[2] + f1.z, v13 = sg1[3] + f1.w; \
  float v20 = sg2[0] + f2.x, v21 = sg2[1] + f2.y, v22 = sg2[2] + f2.z, v23 = sg2[3] + f2.w; \
  float v30 = sg3[0] + f3.x, v31 = sg3[1] + f3.y, v32 = sg3[2] + f3.z, v33 = sg3[3] + f3.w; \
  float mx = fmaxf(fmaxf(fmaxf(v00, v01), fmaxf(v02, v03)), \
                   fmaxf(fmaxf(v10, v11), fmaxf(v12, v13))); \
  mx = fmaxf(mx, fmaxf(fmaxf(fmaxf(v20, v21), fmaxf(v22, v23)), \
                       fmaxf(fmaxf(v30, v31), fmaxf(v32, v33)))); \
  mx = fmaxf(mx, __shfl_xor(mx, 16)); \
  mx = fmaxf(mx, __shfl_xor(mx, 32)); \
  const float mnew = fmaxf(MR, mx); \
  const float alpha = __expf(MR - mnew); \
  MR = mnew; \
  float p00 = __expf(v00 - mnew), p01 = __expf(v01 - mnew), p02 = __expf(v02 - mnew), p03 = __expf(v03 - mnew); \
  float p10 = __expf(v10 - mnew), p11 = __expf(v11 - mnew), p12 = __expf(v12 - mnew), p13 = __expf(v13 - mnew); \
  float p20 = __expf(v20 - mnew), p21 = __expf(v21 - mnew), p22 = __expf(v22 - mnew), p23 = __expf(v23 - mnew); \
  float p30 = __expf(v30 - mnew), p31 = __expf(v31 - mnew), p32 = __expf(v32 - mnew), p33 = __expf(v33 - mnew); \
  { \
    const int swz = 8 * sw; \
    bf16x4 pk; \
    pk[0] = (bf16)p00; pk[1] = (bf16)p01; pk[2] = (bf16)p02; pk[3] = (bf16)p03; \
    *(bf16x4*)(myP + l16 * 64 + ((0 * 16 + quad * 4) ^ swz)) = pk; \
    pk[0] = (bf16)p10; pk[1] = (bf16)p11; pk[2] = (bf16)p12; pk[3] = (bf16)p13; \
    *(bf16x4*)(myP + l16 * 64 + ((1 * 16 + quad * 4) ^ swz)) = pk; \
    pk[0] = (bf16)p20; pk[1] = (bf16)p21; pk[2] = (bf16)p22; pk[3] = (bf16)p23; \
    *(bf16x4*)(myP + l16 * 64 + ((2 * 16 + quad * 4) ^ swz)) = pk; \
    pk[0] = (bf16)p30; pk[1] = (bf16)p31; pk[2] = (bf16)p32; pk[3] = (bf16)p33; \
    *(bf16x4*)(myP + l16 * 64 + ((3 * 16 + quad * 4) ^ swz)) = pk; \
  } \
  float ps = (((p00 + p01) + (p02 + p03)) + ((p10 + p11) + (p12 + p13))) \
           + (((p20 + p21) + (p22 + p23)) + ((p30 + p31) + (p32 + p33))); \
  ps += __shfl_xor(ps, 16); \
  ps += __shfl_xor(ps, 32); \
  LR = LR * alpha + ps; \
  f32x4 av; \
  av[0] = __shfl(alpha, quad * 4 + 0); \
  av[1] = __shfl(alpha, quad * 4 + 1); \
  av[2] = __shfl(alpha, quad * 4 + 2); \
  av[3] = __shfl(alpha, quad * 4 + 3); \
  og0 *= av; og1 *= av; og2 *= av; og3 *= av; }

// ---------------- flash attention: 128-row Q tile, double-buffered K/V prefetch,
// S^T formulation, XOR bank-balanced LDS. One barrier per k-tile.
__global__ void attn_kernel(
    const bf16* __restrict__ Q, const bf16* __restrict__ K,
    const bf16* __restrict__ Vt, const float* __restrict__ mask,
    bf16* __restrict__ ctx) {
  const int b = blockIdx.y >> 4, h = blockIdx.y & 15;
  const int q0 = blockIdx.x * 128;
  __shared__ __align__(16) bf16 lQ[128 * 64];      // Q tile; reused as O tile
  __shared__ __align__(16) bf16 lK[2][64 * 64];    // double-buffered K
  __shared__ __align__(16) bf16 lV[2][64 * 64];    // double-buffered V^T [d][k]
  __shared__ __align__(16) bf16 lP[4][2][16 * 64]; // per-wave per-group P, swizzled
  const int tid = threadIdx.x;
  const int lane = tid & 63, w = tid >> 6;
  const int quad = lane >> 4, l16 = lane & 15;
  const int sr = tid >> 3;
  const int scs = (tid & 7) ^ (sr & 7);   // swizzled source chunk

  const size_t headoff = ((size_t)b * NH_ + h) * S_ * HD_;
  {  // stage Q tile (128 rows, swizzled)
    const bf16* src = Q + headoff + (size_t)q0 * HD_;
#pragma unroll
    for (int c = 0; c < 4; c++)
      async16(src + (c * 32 + sr) * 64 + scs * 8, lQ + c * 2048 + tid * 8);
  }
  {  // stage K/V tile 0 into buffer 0
    const bf16* ksrc = K + headoff;
    async16(ksrc + sr * 64 + scs * 8, lK[0] + tid * 8);
    async16(ksrc + (sr + 32) * 64 + scs * 8, lK[0] + (tid + 256) * 8);
    const bf16* vbase = Vt + headoff;
    async16(vbase + (size_t)sr * S_ + scs * 8, lV[0] + tid * 8);
    async16(vbase + (size_t)(sr + 32) * S_ + scs * 8, lV[0] + (tid + 256) * 8);
  }

  f32x4 oA0 = {}, oA1 = {}, oA2 = {}, oA3 = {};
  f32x4 oB0 = {}, oB1 = {}, oB2 = {}, oB3 = {};
  float mA = -1e30f, lA_ = 0.f, mB = -1e30f, lB_ = 0.f;
  const float* mrowA = mask + ((size_t)b * S_ + q0 + w * 32 + l16) * S_;
  const float* mrowB = mrowA + 16 * S_;
  const int sw = l16 & 7;
  const int pq  = (quad ^ sw) * 8;
  const int pq2 = ((quad + 4) ^ sw) * 8;
  bf16* myPA = lP[w][0];
  bf16* myPB = lP[w][1];

  for (int kt = 0; kt < 32; kt++) {
    const int cur = kt & 1;
    __syncthreads();   // staging for kt complete; buffers of kt-1 free
    if (kt < 31) {     // prefetch kt+1 — lands during this iteration's compute
      const int nxt = cur ^ 1;
      const int k0n = (kt + 1) * 64;
      const bf16* ksrc = K + headoff + (size_t)k0n * HD_;
      async16(ksrc + sr * 64 + scs * 8, lK[nxt] + tid * 8);
      async16(ksrc + (sr + 32) * 64 + scs * 8, lK[nxt] + (tid + 256) * 8);
      const bf16* vbase = Vt + headoff + k0n;
      async16(vbase + (size_t)sr * S_ + scs * 8, lV[nxt] + tid * 8);
      async16(vbase + (size_t)(sr + 32) * S_ + scs * 8, lV[nxt] + (tid + 256) * 8);
    }
    const int k0 = kt * 64;
    const float4* mA4 = (const float4*)(mrowA + k0);
    const float4* mB4 = (const float4*)(mrowB + k0);
    float4 fA0 = mA4[quad], fA1 = mA4[4 + quad], fA2 = mA4[8 + quad], fA3 = mA4[12 + quad];
    float4 fB0 = mB4[quad], fB1 = mB4[4 + quad], fB2 = mB4[8 + quad], fB3 = mB4[12 + quad];

    const bf16* lKc = lK[cur];
    const bf16* lVc = lV[cur];

    // S^T for both groups (shared K frags)
    f32x4 sA0 = {}, sA1 = {}, sA2 = {}, sA3 = {};
    f32x4 sB0 = {}, sB1 = {}, sB2 = {}, sB3 = {};
    {
      bf16x8 bqA = *(const bf16x8*)(lQ + (w * 32 + l16) * 64 + pq);
      bf16x8 bqB = *(const bf16x8*)(lQ + (w * 32 + 16 + l16) * 64 + pq);
      bf16x8 k0f = *(const bf16x8*)(lKc + (0 * 16 + l16) * 64 + pq);
      bf16x8 k1f = *(const bf16x8*)(lKc + (1 * 16 + l16) * 64 + pq);
      bf16x8 k2f = *(const bf16x8*)(lKc + (2 * 16 + l16) * 64 + pq);
      bf16x8 k3f = *(const bf16x8*)(lKc + (3 * 16 + l16) * 64 + pq);
      MM16(k0f, bqA, sA0); MM16(k1f, bqA, sA1); MM16(k2f, bqA, sA2); MM16(k3f, bqA, sA3);
      MM16(k0f, bqB, sB0); MM16(k1f, bqB, sB1); MM16(k2f, bqB, sB2); MM16(k3f, bqB, sB3);
    }
    {
      bf16x8 bqA = *(const bf16x8*)(lQ + (w * 32 + l16) * 64 + pq2);
      bf16x8 bqB = *(const bf16x8*)(lQ + (w * 32 + 16 + l16) * 64 + pq2);
      bf16x8 k0f = *(const bf16x8*)(lKc + (0 * 16 + l16) * 64 + pq2);
      bf16x8 k1f = *(const bf16x8*)(lKc + (1 * 16 + l16) * 64 + pq2);
      bf16x8 k2f = *(const bf16x8*)(lKc + (2 * 16 + l16) * 64 + pq2);
      bf16x8 k3f = *(const bf16x8*)(lKc + (3 * 16 + l16) * 64 + pq2);
      MM16(k0f, bqA, sA0); MM16(k1f, bqA, sA1); MM16(k2f, bqA, sA2); MM16(k3f, bqA, sA3);
      MM16(k0f, bqB, sB0); MM16(k1f, bqB, sB1); MM16(k2f, bqB, sB2); MM16(k3f, bqB, sB3);
    }

    SOFTMAX_G(sA0, sA1, sA2, sA3, fA0, fA1, fA2, fA3, mA, lA_, myPA, oA0, oA1, oA2, oA3)
    SOFTMAX_G(sB0, sB1, sB2, sB3, fB0, fB1, fB2, fB3, mB, lB_, myPB, oB0, oB1, oB2, oB3)

    // O += P V (shared V frags across groups)
    {
      bf16x8 apA = *(const bf16x8*)(myPA + l16 * 64 + pq);
      bf16x8 apB = *(const bf16x8*)(myPB + l16 * 64 + pq);
      bf16x8 b0 = *(const bf16x8*)(lVc + (0 * 16 + l16) * 64 + pq);
      bf16x8 b1 = *(const bf16x8*)(lVc + (1 * 16 + l16) * 64 + pq);
      bf16x8 b2 = *(const bf16x8*)(lVc + (2 * 16 + l16) * 64 + pq);
      bf16x8 b3 = *(const bf16x8*)(lVc + (3 * 16 + l16) * 64 + pq);
      MM16(apA, b0, oA0); MM16(apA, b1, oA1); MM16(apA, b2, oA2); MM16(apA, b3, oA3);
      MM16(apB, b0, oB0); MM16(apB, b1, oB1); MM16(apB, b2, oB2); MM16(apB, b3, oB3);
    }
    {
      bf16x8 apA = *(const bf16x8*)(myPA + l16 * 64 + pq2);
      bf16x8 apB = *(const bf16x8*)(myPB + l16 * 64 + pq2);
      bf16x8 b0 = *(const bf16x8*)(lVc + (0 * 16 + l16) * 64 + pq2);
      bf16x8 b1 = *(const bf16x8*)(lVc + (1 * 16 + l16) * 64 + pq2);
      bf16x8 b2 = *(const bf16x8*)(lVc + (2 * 16 + l16) * 64 + pq2);
      bf16x8 b3 = *(const bf16x8*)(lVc + (3 * 16 + l16) * 64 + pq2);
      MM16(apA, b0, oA0); MM16(apA, b1, oA1); MM16(apA, b2, oA2); MM16(apA, b3, oA3);
      MM16(apB, b0, oB0); MM16(apB, b1, oB1); MM16(apB, b2, oB2); MM16(apB, b3, oB3);
    }
  }

  // epilogue: normalize, both groups into lQ (each wave writes only its own rows)
  f32x4 lvA, lvB;
  lvA[0] = __shfl(lA_, quad * 4 + 0); lvB[0] = __shfl(lB_, quad * 4 + 0);
  lvA[1] = __shfl(lA_, quad * 4 + 1); lvB[1] = __shfl(lB_, quad * 4 + 1);
  lvA[2] = __shfl(lA_, quad * 4 + 2); lvB[2] = __shfl(lB_, quad * 4 + 2);
  lvA[3] = __shfl(lA_, quad * 4 + 3); lvB[3] = __shfl(lB_, quad * 4 + 3);
#pragma unroll
  for (int r = 0; r < 4; r++) {
    const float ia = 1.0f / lvA[r], ib = 1.0f / lvB[r];
    const int sa = w * 32 + quad * 4 + r, sb = sa + 16;
    lQ[sa * 64 + l16]      = (bf16)(oA0[r] * ia);
    lQ[sa * 64 + 16 + l16] = (bf16)(oA1[r] * ia);
    lQ[sa * 64 + 32 + l16] = (bf16)(oA2[r] * ia);
    lQ[sa * 64 + 48 + l16] = (bf16)(oA3[r] * ia);
    lQ[sb * 64 + l16]      = (bf16)(oB0[r] * ib);
    lQ[sb * 64 + 16 + l16] = (bf16)(oB1[r] * ib);
    lQ[sb * 64 + 32 + l16] = (bf16)(oB2[r] * ib);
    lQ[sb * 64 + 48 + l16] = (bf16)(oB3[r] * ib);
  }
  __syncthreads();
  {
    const int cc = tid & 7;
#pragma unroll
    for (int it = 0; it < 4; it++) {
      int row = it * 32 + sr;
      bf16x8 v = *(const bf16x8*)(lQ + row * 64 + cc * 8);
      *(bf16x8*)(ctx + ((size_t)b * S_ + q0 + row) * HID_ + h * HD_ + cc * 8) = v;
    }
  }
}

#define PW(i, j, C) { \
  float* po = out + (size_t)(m0 + wm + (i) * 16 + quad * 4) * 1024 + n0 + wn + (j) * 16 + l16; \
  po[0] = C[0]; po[1024] = C[1]; po[2048] = C[2]; po[3072] = C[3]; }

// ---------------- output projection: out(fp32) = ctx @ Wo^T
__global__ void proj_gemm(
    const bf16* __restrict__ A, const bf16* __restrict__ Wo, float* __restrict__ out) {
  const int m0 = blockIdx.y * 128;
  const int n0 = blockIdx.x * 128;
  __shared__ __align__(16) bf16 lA[128 * 32];
  __shared__ __align__(16) bf16 lB[128 * 32];
  const int tid = threadIdx.x;
  const int lane = tid & 63, w = tid >> 6;
  const int wm = (w >> 1) * 64, wn = (w & 1) * 64;
  const int quad = lane >> 4, l16 = lane & 15;

  DECL_ACC
  const int qa = tid, qb = tid + 256;
  const int ra = qa >> 2, ca = (qa & 3) * 8;
  const int rb = qb >> 2, cb = (qb & 3) * 8;

  for (int k0 = 0; k0 < 1024; k0 += 32) {
    async16(A + (size_t)(m0 + ra) * 1024 + k0 + ca, lA + qa * 8);
    async16(A + (size_t)(m0 + rb) * 1024 + k0 + cb, lA + qb * 8);
    async16(Wo + (size_t)(n0 + ra) * 1024 + k0 + ca, lB + qa * 8);
    async16(Wo + (size_t)(n0 + rb) * 1024 + k0 + cb, lB + qb * 8);
    __syncthreads();
    KLOOP_FRAGS_MFMA
    __syncthreads();
  }
  PW(0, 0, a00) PW(0, 1, a01) PW(0, 2, a02) PW(0, 3, a03)
  PW(1, 0, a10) PW(1, 1, a11) PW(1, 2, a12) PW(1, 3, a13)
  PW(2, 0, a20) PW(2, 1, a21) PW(2, 2, a22) PW(2, 3, a23)
  PW(3, 0, a30) PW(3, 1, a31) PW(3, 2, a32) PW(3, 3, a33)
}

__global__ void sentinel_kernel(float* out, int n, float val) {
  int i = blockIdx.x * 256 + threadIdx.x;
  if (i < n) out[i] = val;
}

extern "C" void kernel_launch(void* const* d_in, const int* in_sizes, int n_in,
                              void* d_out, int out_size, void* d_ws, size_t ws_size,
                              hipStream_t stream) {
  const float* X    = (const float*)d_in[0];
  const float* mask = (const float*)d_in[1];
  const int*   pos  = (const int*)d_in[2];
  const float* Wq   = (const float*)d_in[3];
  const float* Wk   = (const float*)d_in[4];
  const float* Wv   = (const float*)d_in[5];
  const float* Wo   = (const float*)d_in[6];
  float* out = (float*)d_out;

  char* ws = (char*)d_ws;
  const size_t SZ = (size_t)B_ * NH_ * S_ * HD_ * sizeof(bf16);  // 16 MiB
  if (ws_size < 3 * SZ) {
    sentinel_kernel<<<(out_size + 255) / 256, 256, 0, stream>>>(
        out, out_size, (float)(ws_size >> 20));
    return;
  }

  // ws layout (48 MiB): [0,16M) Xb then ctx; [16M,32M) Q; [32M,48M) Vt then Wob.
  bf16* Xb  = (bf16*)(ws);
  bf16* ctx = (bf16*)(ws);
  bf16* Q   = (bf16*)(ws + SZ);
  bf16* Vt  = (bf16*)(ws + 2 * SZ);
  bf16* Wob = (bf16*)(ws + 2 * SZ);
  // d_out hosts bf16 K [0,16M) and Wq/Wk/Wv bf16 [16M,22M) until proj overwrites.
  bf16* Kb  = (bf16*)d_out;
  bf16* Wqb = (bf16*)((char*)d_out + SZ);
  bf16* Wkb = Wqb + 1024 * 1024;
  bf16* Wvb = Wkb + 1024 * 1024;

  const int nX4 = (B_ * S_ * HID_) / 4;
  const int nW4 = (HID_ * HID_) / 4;
  cvt_kernel<<<(nX4 + 255) / 256, 256, 0, stream>>>(X, Xb, nX4);
  cvt_kernel<<<(nW4 + 255) / 256, 256, 0, stream>>>(Wq, Wqb, nW4);
  cvt_kernel<<<(nW4 + 255) / 256, 256, 0, stream>>>(Wk, Wkb, nW4);
  cvt_kernel<<<(nW4 + 255) / 256, 256, 0, stream>>>(Wv, Wvb, nW4);

  qkv_gemm<<<dim3(8, 64, 3), 256, 0, stream>>>(Xb, Wqb, Wkb, Wvb, pos, Q, Kb, Vt);
  attn_kernel<<<dim3(16, 64), 256, 0, stream>>>(Q, Kb, Vt, mask, ctx);

  cvt_kernel<<<(nW4 + 255) / 256, 256, 0, stream>>>(Wo, Wob, nW4);
  proj_gemm<<<dim3(8, 64), 256, 0, stream>>>(ctx, Wob, out);
}